// Round 9
// baseline (221.334 us; speedup 1.0000x reference)
//
#include <hip/hip_runtime.h>

// ---------------------------------------------------------------------------
// RelGraphConv x3 + action mask, MI355X (gfx950) — round 9
// R8: binned scatter fixed the write-amplified scatter (55us -> gone); our
// kernels left the profile top-5 (now harness ws-poison fills). Remaining
// co-leaders are the two bucket-gather kernels (latency-bound, ~2.3 rounds
// of 8 outstanding loads). This round: 16 outstanding predicated loads per
// round (ids clamped, results weighted x0/1) -> ~1.4 rounds/node.
// ---------------------------------------------------------------------------

#define STRIDE 64    // bucket capacity; P(deg>=64) astronomically small
#define BINCAP 2560  // records per bin; mean 2048, sigma~45 -> 11 sigma margin

typedef unsigned short ushortT;
typedef __attribute__((ext_vector_type(8))) short short8;   // 8 bf16 (4 VGPRs)
typedef __attribute__((ext_vector_type(4))) float f32x4;    // MFMA C/D

__device__ inline ushortT f2bf(float f) {
    union { float f; unsigned u; } v; v.f = f;
    unsigned r = v.u + 0x7FFFu + ((v.u >> 16) & 1u);   // RNE
    return (ushortT)(r >> 16);
}
__device__ inline float bf2f(ushortT h) {
    union { unsigned u; float f; } v; v.u = ((unsigned)h) << 16;
    return v.f;
}

__device__ inline void atomicMinF(float* addr, float v) {
    if (v >= 0.f) atomicMin((int*)addr, __float_as_int(v));
    else          atomicMax((unsigned int*)addr, __float_as_uint(v));
}

// ---- K0: weight pack + bincnt/minval init (tiny, runs before everything) ---
__global__ __launch_bounds__(256) void pack_init_kernel(
    const float* __restrict__ W1, const float* __restrict__ loop1,
    const float* __restrict__ W2, const float* __restrict__ loop2,
    ushortT* __restrict__ BP1, ushortT* __restrict__ BP2,
    int* __restrict__ bincnt, float* __restrict__ minval, int NBINS) {
    int g = (int)blockIdx.x * 256 + (int)threadIdx.x;  // 0..4607
    if (g < NBINS) bincnt[g] = 0;
    if (g == 0) *(int*)minval = 0x7f7f7f7f;            // 3.39e38
    if (g < 3072) {
        // layer 1: 12 ct x 4 ks x 64 lanes
        int l = g & 63, ks = (g >> 6) & 3, ct = g >> 8;
        int c = ct * 16 + (l & 15);
        int mat = c >> 6, cc = c & 63;
        int kbase = ks * 32 + (l >> 4) * 8;
        ushortT* dstp = BP1 + (size_t)g * 8;
#pragma unroll
        for (int j = 0; j < 8; ++j) {
            int k = kbase + j;
            float v = (mat < 2) ? W1[((size_t)mat * 128 + k) * 64 + cc]
                                : loop1[(size_t)k * 64 + cc];
            dstp[j] = f2bf(v);
        }
    } else {
        // layer 2: 12 ct x 2 ks x 64 lanes
        int s = g - 3072;
        int l = s & 63, ks = (s >> 6) & 1, ct = s >> 7;
        int c = ct * 16 + (l & 15);
        int mat = c >> 6, cc = c & 63;
        int kbase = ks * 32 + (l >> 4) * 8;
        ushortT* dstp = BP2 + (size_t)s * 8;
#pragma unroll
        for (int j = 0; j < 8; ++j) {
            int k = kbase + j;
            float v = (mat < 2) ? W2[((size_t)mat * 64 + k) * 64 + cc]
                                : loop2[(size_t)k * 64 + cc];
            dstp[j] = f2bf(v);
        }
    }
}

// ---- K1: phaseA-binning [0,NBA) | gemm1 [NBA, NBA+NTILES) ------------------
__global__ __launch_bounds__(256) void k1_kernel(
    const float* __restrict__ x, const ushortT* __restrict__ BP1,
    const float* __restrict__ b1,
    ushortT* __restrict__ hrelb, ushortT* __restrict__ H1b,
    const int* __restrict__ src, const int* __restrict__ dst,
    const int* __restrict__ et, int* __restrict__ bincnt, int2* __restrict__ binbuf,
    int N, int E, int NBINS, int NBA) {
    __shared__ int hist[512];
    __shared__ int gbase[512];
    __shared__ ushortT rnk[4096];

    const int t = (int)threadIdx.x;

    if ((int)blockIdx.x < NBA) {
        // ---- phase A: bin 4096 edges ---------------------------------------
        for (int i = t; i < NBINS; i += 256) hist[i] = 0;
        __syncthreads();
        const int base = (int)blockIdx.x * 4096;
#pragma unroll
        for (int i = 0; i < 16; ++i) {
            int e = base + t + i * 256;
            if (e < E) {
                int bb = dst[e] >> 7;
                rnk[t + i * 256] = (ushortT)atomicAdd(&hist[bb], 1);
            }
        }
        __syncthreads();
        for (int i = t; i < NBINS; i += 256) {
            int h = hist[i];
            gbase[i] = h ? atomicAdd(&bincnt[i], h) : 0;
        }
        __syncthreads();
#pragma unroll
        for (int i = 0; i < 16; ++i) {
            int e = base + t + i * 256;
            if (e < E) {
                int dd = dst[e];
                int bb = dd >> 7;
                int v = et[e] * N + src[e];
                int pos = gbase[bb] + (int)rnk[t + i * 256];
                if (pos < BINCAP)
                    binbuf[(size_t)bb * BINCAP + pos] = make_int2(dd, v);
            }
        }
        return;
    }
    // ---- gemm1 (MFMA): wave = 16 nodes x 192 cols, K=128 -------------------
    const int w = t >> 6, lane = t & 63;
    const int rowbase = (((int)blockIdx.x - NBA) * 4 + w) * 16;
    const int m = lane & 15, quad = lane >> 4;
    const int nclamp = min(rowbase + m, N - 1);

    short8 a[4];
    const float* xp = x + (size_t)nclamp * 128 + quad * 8;
#pragma unroll
    for (int ks = 0; ks < 4; ++ks) {
        float4 g0 = *(const float4*)(xp + ks * 32);
        float4 g1 = *(const float4*)(xp + ks * 32 + 4);
        a[ks][0] = (short)f2bf(g0.x); a[ks][1] = (short)f2bf(g0.y);
        a[ks][2] = (short)f2bf(g0.z); a[ks][3] = (short)f2bf(g0.w);
        a[ks][4] = (short)f2bf(g1.x); a[ks][5] = (short)f2bf(g1.y);
        a[ks][6] = (short)f2bf(g1.z); a[ks][7] = (short)f2bf(g1.w);
    }

    f32x4 acc[12];
#pragma unroll
    for (int ct = 0; ct < 12; ++ct) acc[ct] = (f32x4){0.f, 0.f, 0.f, 0.f};

#pragma unroll
    for (int ks = 0; ks < 4; ++ks) {
#pragma unroll
        for (int ct = 0; ct < 12; ++ct) {
            short8 b = *(const short8*)&BP1[((size_t)(ct * 4 + ks) * 64 + lane) * 8];
            acc[ct] = __builtin_amdgcn_mfma_f32_16x16x32_bf16(a[ks], b, acc[ct], 0, 0, 0);
        }
    }

    const int node0 = rowbase + quad * 4;
#pragma unroll
    for (int ct = 0; ct < 12; ++ct) {
        int c = ct * 16 + m;
        int mat = c >> 6, cc = c & 63;
        float bias = (mat == 2) ? b1[cc] : 0.f;
#pragma unroll
        for (int j = 0; j < 4; ++j) {
            int n = node0 + j;
            if (n < N) {
                float v = acc[ct][j] + bias;
                if (mat < 2) hrelb[((size_t)mat * N + n) * 64 + cc] = f2bf(v);
                else         H1b[(size_t)n * 64 + cc] = f2bf(v);
            }
        }
    }
}

// ---- K2: phase B — block per bin, LDS counting, local eidx writes ----------
__global__ __launch_bounds__(256) void phaseB_kernel(
    const int* __restrict__ bincnt, const int2* __restrict__ binbuf,
    int* __restrict__ cnt, int* __restrict__ eidx, int N) {
    __shared__ int lcnt[128];
    const int b = (int)blockIdx.x;
    const int t = (int)threadIdx.x;
    if (t < 128) lcnt[t] = 0;
    __syncthreads();
    const int cb = min(bincnt[b], BINCAP);
    const int2* buf = binbuf + (size_t)b * BINCAP;
    for (int i = t; i < cb; i += 256) {
        int2 rec = buf[i];
        int r = atomicAdd(&lcnt[rec.x & 127], 1);
        if (r < STRIDE) eidx[(size_t)rec.x * STRIDE + r] = rec.y;
    }
    __syncthreads();
    int node = b * 128 + t;
    if (t < 128 && node < N) cnt[node] = min(lcnt[t], STRIDE);
}

// ---- gather body: 16 predicated outstanding loads per round ----------------
__device__ __forceinline__ float gather_accum(
    const ushortT* __restrict__ hb, int my, int deg, int lane, float acc) {
    for (int j = 0; j < deg; j += 16) {
        float v[16];
#pragma unroll
        for (int q = 0; q < 16; ++q) {
            int jj = j + q;
            int sel = (jj < deg) ? jj : 0;           // clamp to edge 0
            int id = __shfl(my, sel, 64);
            float wgt = (jj < deg) ? 1.f : 0.f;
            v[q] = wgt * bf2f(hb[(size_t)id * 64 + lane]);
        }
        float s0 = (v[0] + v[1]) + (v[2] + v[3]);
        float s1 = (v[4] + v[5]) + (v[6] + v[7]);
        float s2 = (v[8] + v[9]) + (v[10] + v[11]);
        float s3 = (v[12] + v[13]) + (v[14] + v[15]);
        acc += (s0 + s1) + (s2 + s3);
    }
    return acc;
}

// ---- agg1: wave per node, lane = channel ------------------------------------
__global__ void agg1_kernel(const ushortT* __restrict__ hrelb, const int* __restrict__ eidx,
                            const int* __restrict__ cnt, ushortT* __restrict__ H1b, int N) {
    int node = (int)blockIdx.x * 4 + ((int)threadIdx.x >> 6);
    if (node >= N) return;
    int lane = (int)threadIdx.x & 63;
    int deg = cnt[node];
    int my = (lane < deg) ? eidx[(size_t)node * STRIDE + lane] : 0;
    float acc = bf2f(H1b[(size_t)node * 64 + lane]);
    acc = gather_accum(hrelb, my, deg, lane, acc);
    H1b[(size_t)node * 64 + lane] = f2bf(fmaxf(acc, 0.f));
}

// ---- gemm2 (MFMA): wave = 16 nodes x 192 cols, K=64, bf16 A from H1b -------
__global__ __launch_bounds__(256) void gemm2_mfma(
    const ushortT* __restrict__ H1b, const ushortT* __restrict__ BP2,
    const float* __restrict__ b2,
    ushortT* __restrict__ hrel2b, ushortT* __restrict__ H2b, int N) {
    const int w = (int)threadIdx.x >> 6, lane = (int)threadIdx.x & 63;
    const int rowbase = ((int)blockIdx.x * 4 + w) * 16;
    const int m = lane & 15, quad = lane >> 4;
    const int nclamp = min(rowbase + m, N - 1);

    short8 a[2];
    const ushortT* hp = H1b + (size_t)nclamp * 64 + quad * 8;
    a[0] = *(const short8*)(hp);
    a[1] = *(const short8*)(hp + 32);

    f32x4 acc[12];
#pragma unroll
    for (int ct = 0; ct < 12; ++ct) acc[ct] = (f32x4){0.f, 0.f, 0.f, 0.f};

#pragma unroll
    for (int ks = 0; ks < 2; ++ks) {
#pragma unroll
        for (int ct = 0; ct < 12; ++ct) {
            short8 b = *(const short8*)&BP2[((size_t)(ct * 2 + ks) * 64 + lane) * 8];
            acc[ct] = __builtin_amdgcn_mfma_f32_16x16x32_bf16(a[ks], b, acc[ct], 0, 0, 0);
        }
    }

    const int node0 = rowbase + quad * 4;
#pragma unroll
    for (int ct = 0; ct < 12; ++ct) {
        int c = ct * 16 + m;
        int mat = c >> 6, cc = c & 63;
        float bias = (mat == 2) ? b2[cc] : 0.f;
#pragma unroll
        for (int j = 0; j < 4; ++j) {
            int n = node0 + j;
            if (n < N) {
                float v = acc[ct][j] + bias;
                if (mat < 2) hrel2b[((size_t)mat * N + n) * 64 + cc] = f2bf(v);
                else         H2b[(size_t)n * 64 + cc] = f2bf(v);
            }
        }
    }
}

// ---- K3: fused agg(layer2) + gemm(layer3, out=2), wave per node ------------
__global__ void k3_kernel(const ushortT* __restrict__ hrel2b, const ushortT* __restrict__ H2b,
                          const int* __restrict__ eidx, const int* __restrict__ cnt,
                          const float* __restrict__ W3, const float* __restrict__ loop3,
                          const float* __restrict__ b3,
                          float* __restrict__ hrel3, float* __restrict__ H3, int N) {
    int node = (int)blockIdx.x * 4 + ((int)threadIdx.x >> 6);
    if (node >= N) return;
    int lane = (int)threadIdx.x & 63;
    int deg = cnt[node];
    int my = (lane < deg) ? eidx[(size_t)node * STRIDE + lane] : 0;
    float acc = bf2f(H2b[(size_t)node * 64 + lane]);
    acc = gather_accum(hrel2b, my, deg, lane, acc);
    float xk = fmaxf(acc, 0.f);  // relu(layer-2 out), lane = k
    float p[6];
    p[0] = xk * W3[lane * 2 + 0];
    p[1] = xk * W3[lane * 2 + 1];
    p[2] = xk * W3[(64 + lane) * 2 + 0];
    p[3] = xk * W3[(64 + lane) * 2 + 1];
    p[4] = xk * loop3[lane * 2 + 0];
    p[5] = xk * loop3[lane * 2 + 1];
#pragma unroll
    for (int mm = 32; mm >= 1; mm >>= 1) {
#pragma unroll
        for (int q = 0; q < 6; ++q) p[q] += __shfl_xor(p[q], mm, 64);
    }
    if (lane == 0) {
        hrel3[(size_t)node * 2 + 0] = p[0];
        hrel3[(size_t)node * 2 + 1] = p[1];
        hrel3[((size_t)N + node) * 2 + 0] = p[2];
        hrel3[((size_t)N + node) * 2 + 1] = p[3];
        H3[(size_t)node * 2 + 0] = p[4] + b3[0];
        H3[(size_t)node * 2 + 1] = p[5] + b3[1];
    }
}

// ---- K4: layer-3 aggregation + global min (8 predicated outstanding) -------
__global__ void agg3min_kernel(const float* __restrict__ hrel3, const int* __restrict__ eidx,
                               const int* __restrict__ cnt, float* __restrict__ H3,
                               float* __restrict__ minval, int N) {
    int n = (int)blockIdx.x * 256 + (int)threadIdx.x;
    float v = 3.4e38f;
    if (n < N) {
        float a0 = H3[n * 2 + 0], a1 = H3[n * 2 + 1];
        int deg = cnt[n];
        const int* row = &eidx[(size_t)n * STRIDE];
        for (int j = 0; j < deg; j += 8) {
            float2 q[8];
            float wg[8];
#pragma unroll
            for (int qq = 0; qq < 8; ++qq) {
                int jj = j + qq;
                int sel = (jj < deg) ? jj : 0;
                int idx = row[sel];
                wg[qq] = (jj < deg) ? 1.f : 0.f;
                q[qq] = *(const float2*)&hrel3[(size_t)idx * 2];
            }
#pragma unroll
            for (int qq = 0; qq < 8; ++qq) {
                a0 += wg[qq] * q[qq].x;
                a1 += wg[qq] * q[qq].y;
            }
        }
        H3[n * 2 + 0] = a0;
        H3[n * 2 + 1] = a1;
        v = fminf(a0, a1);
    }
#pragma unroll
    for (int mm = 32; mm >= 1; mm >>= 1) v = fminf(v, __shfl_xor(v, mm, 64));
    __shared__ float s[4];
    if ((threadIdx.x & 63) == 0) s[threadIdx.x >> 6] = v;
    __syncthreads();
    if (threadIdx.x == 0)
        atomicMinF(minval, fminf(fminf(s[0], s[1]), fminf(s[2], s[3])));
}

__global__ void mask_kernel(const float* __restrict__ H3, const float* __restrict__ minval,
                            const int* __restrict__ cs, const int* __restrict__ ms,
                            float* __restrict__ out, int N) {
    int n = (int)blockIdx.x * 256 + (int)threadIdx.x;
    if (n >= N) return;
    float m = minval[0] - 1.0f;
    bool up = cs[n] >= ms[n] - 1;
    bool lo = cs[n] == 0;
    out[n * 2 + 0] = up ? m : H3[n * 2 + 0];
    out[n * 2 + 1] = lo ? m : H3[n * 2 + 1];
}

// ---------------------------------------------------------------------------
extern "C" void kernel_launch(void* const* d_in, const int* in_sizes, int n_in,
                              void* d_out, int out_size, void* d_ws, size_t ws_size,
                              hipStream_t stream) {
    const float* x     = (const float*)d_in[0];
    const int* src     = (const int*)d_in[1];
    const int* dst     = (const int*)d_in[2];
    const int* etypes  = (const int*)d_in[3];
    const int* cellsz  = (const int*)d_in[4];
    const int* maxsz   = (const int*)d_in[5];
    const float* W1    = (const float*)d_in[6];
    const float* loop1 = (const float*)d_in[7];
    const float* b1    = (const float*)d_in[8];
    const float* W2    = (const float*)d_in[9];
    const float* loop2 = (const float*)d_in[10];
    const float* b2    = (const float*)d_in[11];
    const float* W3    = (const float*)d_in[12];
    const float* loop3 = (const float*)d_in[13];
    const float* b3    = (const float*)d_in[14];
    float* out = (float*)d_out;

    const int N = in_sizes[0] / 128;  // 50000
    const int E = in_sizes[1];        // 800000

    char* p = (char*)d_ws;
    auto alloc = [&](size_t bytes) -> void* {
        void* r = (void*)p;
        p += ((bytes + 255) / 256) * 256;
        return r;
    };
    ushortT* hrelb  = (ushortT*)alloc((size_t)2 * N * 64 * 2);  // 12.8 MB bf16
    ushortT* H1b    = (ushortT*)alloc((size_t)N * 64 * 2);      //  6.4 MB bf16
    ushortT* hrel2b = (ushortT*)alloc((size_t)2 * N * 64 * 2);  // 12.8 MB bf16
    ushortT* H2b    = (ushortT*)alloc((size_t)N * 64 * 2);      //  6.4 MB bf16
    float* hrel3    = (float*)alloc((size_t)2 * N * 2 * 4);
    float* H3       = (float*)alloc((size_t)N * 2 * 4);
    int* cnt        = (int*)alloc((size_t)N * 4);
    int* eidx       = (int*)alloc((size_t)N * STRIDE * 4);      // 12.8 MB
    ushortT* BP1    = (ushortT*)alloc((size_t)3072 * 8 * 2);    // 48 KB frag-packed
    ushortT* BP2    = (ushortT*)alloc((size_t)1536 * 8 * 2);    // 24 KB
    float* minval   = (float*)alloc(4);

    const int NBINS = (N + 127) >> 7;                           // 391
    int* bincnt     = (int*)alloc((size_t)NBINS * 4);
    int2* binbuf    = (int2*)alloc((size_t)NBINS * BINCAP * 8); // 8.0 MB
    (void)ws_size; (void)n_in; (void)out_size;

    const int NB_N   = (N + 255) / 256;      // 196
    const int NTILES = (N + 63) / 64;        // 782
    const int NB_W   = (N + 3) / 4;          // 12500
    const int NBA    = (E + 4095) / 4096;    // 196 phase-A blocks

    // K0: weight pack + bincnt/minval init (separate launch: producer ordering)
    pack_init_kernel<<<18, 256, 0, stream>>>(
        W1, loop1, W2, loop2, BP1, BP2, bincnt, minval, NBINS);

    // K1: phase-A binning || layer-1 MFMA GEMM (independent halves)
    k1_kernel<<<NBA + NTILES, 256, 0, stream>>>(
        x, BP1, b1, hrelb, H1b,
        src, dst, etypes, bincnt, binbuf, N, E, NBINS, NBA);

    // K2: phase B — bin-local scatter into eidx buckets + cnt
    phaseB_kernel<<<NBINS, 256, 0, stream>>>(bincnt, binbuf, cnt, eidx, N);

    // layer-1 aggregation: wave per node (16 outstanding gathers)
    agg1_kernel<<<NB_W, 256, 0, stream>>>(hrelb, eidx, cnt, H1b, N);

    // layer-2 GEMM (MFMA)
    gemm2_mfma<<<NTILES, 256, 0, stream>>>(H1b, BP2, b2, hrel2b, H2b, N);

    // fused agg(layer2) + gemm(layer3)
    k3_kernel<<<NB_W, 256, 0, stream>>>(hrel2b, H2b, eidx, cnt, W3, loop3, b3,
                                        hrel3, H3, N);

    // layer-3 aggregation + global min, then mask
    agg3min_kernel<<<NB_N, 256, 0, stream>>>(hrel3, eidx, cnt, H3, minval, N);
    mask_kernel<<<NB_N, 256, 0, stream>>>(H3, minval, cellsz, maxsz, out, N);
}

// Round 10
// 218.571 us; speedup vs baseline: 1.0126x; 1.0126x over previous
//
#include <hip/hip_runtime.h>

// ---------------------------------------------------------------------------
// RelGraphConv x3 + action mask, MI355X (gfx950) — round 10
// R9: 16-outstanding gather was NEUTRAL -> gathers are CU-queue x latency
// bound, not wave-MLP bound. Lever: shrink the gathered working set.
// Aggregate-first layer 2 (linearity): agg2 gathers H1b (6.4MB ws, was
// hrel2b 12.8MB) into per-rel sums S0/S1; gemm23 then does the K=192 MFMA
// for H2 AND layer-3's 6-col transform in-register (butterfly over col
// lanes) -> hrel3/H3. Deletes gemm2 kernel + hrel2b/H2b round trips.
// ---------------------------------------------------------------------------

#define STRIDE 64    // bucket capacity; P(deg>=64) astronomically small
#define BINCAP 2560  // records per bin; mean 2048, sigma~45 -> 11 sigma margin

typedef unsigned short ushortT;
typedef __attribute__((ext_vector_type(8))) short short8;   // 8 bf16 (4 VGPRs)
typedef __attribute__((ext_vector_type(4))) float f32x4;    // MFMA C/D

__device__ inline ushortT f2bf(float f) {
    union { float f; unsigned u; } v; v.f = f;
    unsigned r = v.u + 0x7FFFu + ((v.u >> 16) & 1u);   // RNE
    return (ushortT)(r >> 16);
}
__device__ inline float bf2f(ushortT h) {
    union { unsigned u; float f; } v; v.u = ((unsigned)h) << 16;
    return v.f;
}

__device__ inline void atomicMinF(float* addr, float v) {
    if (v >= 0.f) atomicMin((int*)addr, __float_as_int(v));
    else          atomicMax((unsigned int*)addr, __float_as_uint(v));
}

// ---- K0: weight pack + bincnt/minval init (tiny, runs before everything) ---
// BP1: layer-1 [W1_0;W1_1;loop1] 12ct x 4ks. BP2: layer-2 K=192 [W2_0;W2_1;
// loop2] packed as 4ct x 6ks (64 output cols).
__global__ __launch_bounds__(256) void pack_init_kernel(
    const float* __restrict__ W1, const float* __restrict__ loop1,
    const float* __restrict__ W2, const float* __restrict__ loop2,
    ushortT* __restrict__ BP1, ushortT* __restrict__ BP2,
    int* __restrict__ bincnt, float* __restrict__ minval, int NBINS) {
    int g = (int)blockIdx.x * 256 + (int)threadIdx.x;  // 0..4607
    if (g < NBINS) bincnt[g] = 0;
    if (g == 0) *(int*)minval = 0x7f7f7f7f;            // 3.39e38
    if (g < 3072) {
        // layer 1: 12 ct x 4 ks x 64 lanes
        int l = g & 63, ks = (g >> 6) & 3, ct = g >> 8;
        int c = ct * 16 + (l & 15);
        int mat = c >> 6, cc = c & 63;
        int kbase = ks * 32 + (l >> 4) * 8;
        ushortT* dstp = BP1 + (size_t)g * 8;
#pragma unroll
        for (int j = 0; j < 8; ++j) {
            int k = kbase + j;
            float v = (mat < 2) ? W1[((size_t)mat * 128 + k) * 64 + cc]
                                : loop1[(size_t)k * 64 + cc];
            dstp[j] = f2bf(v);
        }
    } else {
        // layer 2 (K=192): slot s = ct*384 + ks*64 + l, ct in 0..3, ks in 0..5
        int s = g - 3072;                 // 0..1535
        int l = s & 63;
        int ks = (s >> 6) % 6;
        int ct = s / 384;
        int c = ct * 16 + (l & 15);       // output col 0..63
        int kbase = ks * 32 + (l >> 4) * 8;
        ushortT* dstp = BP2 + (size_t)s * 8;
#pragma unroll
        for (int j = 0; j < 8; ++j) {
            int k = kbase + j;            // 0..191: [W2_0 | W2_1 | loop2]
            float v = (k < 128) ? W2[(size_t)k * 64 + c]
                                : loop2[(size_t)(k - 128) * 64 + c];
            dstp[j] = f2bf(v);
        }
    }
}

// ---- K1: phaseA-binning [0,NBA) | gemm1 [NBA, NBA+NTILES) ------------------
__global__ __launch_bounds__(256) void k1_kernel(
    const float* __restrict__ x, const ushortT* __restrict__ BP1,
    const float* __restrict__ b1,
    ushortT* __restrict__ hrelb, ushortT* __restrict__ H1b,
    const int* __restrict__ src, const int* __restrict__ dst,
    const int* __restrict__ et, int* __restrict__ bincnt, int2* __restrict__ binbuf,
    int N, int E, int NBINS, int NBA) {
    __shared__ int hist[512];
    __shared__ int gbase[512];
    __shared__ ushortT rnk[4096];

    const int t = (int)threadIdx.x;

    if ((int)blockIdx.x < NBA) {
        // ---- phase A: bin 4096 edges ---------------------------------------
        for (int i = t; i < NBINS; i += 256) hist[i] = 0;
        __syncthreads();
        const int base = (int)blockIdx.x * 4096;
#pragma unroll
        for (int i = 0; i < 16; ++i) {
            int e = base + t + i * 256;
            if (e < E) {
                int bb = dst[e] >> 7;
                rnk[t + i * 256] = (ushortT)atomicAdd(&hist[bb], 1);
            }
        }
        __syncthreads();
        for (int i = t; i < NBINS; i += 256) {
            int h = hist[i];
            gbase[i] = h ? atomicAdd(&bincnt[i], h) : 0;
        }
        __syncthreads();
#pragma unroll
        for (int i = 0; i < 16; ++i) {
            int e = base + t + i * 256;
            if (e < E) {
                int dd = dst[e];
                int bb = dd >> 7;
                int v = et[e] * N + src[e];
                int pos = gbase[bb] + (int)rnk[t + i * 256];
                if (pos < BINCAP)
                    binbuf[(size_t)bb * BINCAP + pos] = make_int2(dd, v);
            }
        }
        return;
    }
    // ---- gemm1 (MFMA): wave = 16 nodes x 192 cols, K=128 -------------------
    const int w = t >> 6, lane = t & 63;
    const int rowbase = (((int)blockIdx.x - NBA) * 4 + w) * 16;
    const int m = lane & 15, quad = lane >> 4;
    const int nclamp = min(rowbase + m, N - 1);

    short8 a[4];
    const float* xp = x + (size_t)nclamp * 128 + quad * 8;
#pragma unroll
    for (int ks = 0; ks < 4; ++ks) {
        float4 g0 = *(const float4*)(xp + ks * 32);
        float4 g1 = *(const float4*)(xp + ks * 32 + 4);
        a[ks][0] = (short)f2bf(g0.x); a[ks][1] = (short)f2bf(g0.y);
        a[ks][2] = (short)f2bf(g0.z); a[ks][3] = (short)f2bf(g0.w);
        a[ks][4] = (short)f2bf(g1.x); a[ks][5] = (short)f2bf(g1.y);
        a[ks][6] = (short)f2bf(g1.z); a[ks][7] = (short)f2bf(g1.w);
    }

    f32x4 acc[12];
#pragma unroll
    for (int ct = 0; ct < 12; ++ct) acc[ct] = (f32x4){0.f, 0.f, 0.f, 0.f};

#pragma unroll
    for (int ks = 0; ks < 4; ++ks) {
#pragma unroll
        for (int ct = 0; ct < 12; ++ct) {
            short8 b = *(const short8*)&BP1[((size_t)(ct * 4 + ks) * 64 + lane) * 8];
            acc[ct] = __builtin_amdgcn_mfma_f32_16x16x32_bf16(a[ks], b, acc[ct], 0, 0, 0);
        }
    }

    const int node0 = rowbase + quad * 4;
#pragma unroll
    for (int ct = 0; ct < 12; ++ct) {
        int c = ct * 16 + m;
        int mat = c >> 6, cc = c & 63;
        float bias = (mat == 2) ? b1[cc] : 0.f;
#pragma unroll
        for (int j = 0; j < 4; ++j) {
            int n = node0 + j;
            if (n < N) {
                float v = acc[ct][j] + bias;
                if (mat < 2) hrelb[((size_t)mat * N + n) * 64 + cc] = f2bf(v);
                else         H1b[(size_t)n * 64 + cc] = f2bf(v);
            }
        }
    }
}

// ---- K2: phase B — block per bin, LDS counting, local eidx writes ----------
__global__ __launch_bounds__(256) void phaseB_kernel(
    const int* __restrict__ bincnt, const int2* __restrict__ binbuf,
    int* __restrict__ cnt, int* __restrict__ eidx, int N) {
    __shared__ int lcnt[128];
    const int b = (int)blockIdx.x;
    const int t = (int)threadIdx.x;
    if (t < 128) lcnt[t] = 0;
    __syncthreads();
    const int cb = min(bincnt[b], BINCAP);
    const int2* buf = binbuf + (size_t)b * BINCAP;
    for (int i = t; i < cb; i += 256) {
        int2 rec = buf[i];
        int r = atomicAdd(&lcnt[rec.x & 127], 1);
        if (r < STRIDE) eidx[(size_t)rec.x * STRIDE + r] = rec.y;
    }
    __syncthreads();
    int node = b * 128 + t;
    if (t < 128 && node < N) cnt[node] = min(lcnt[t], STRIDE);
}

// ---- gather body: 16 predicated outstanding loads per round ----------------
__device__ __forceinline__ float gather_accum(
    const ushortT* __restrict__ hb, int my, int deg, int lane, float acc) {
    for (int j = 0; j < deg; j += 16) {
        float v[16];
#pragma unroll
        for (int q = 0; q < 16; ++q) {
            int jj = j + q;
            int sel = (jj < deg) ? jj : 0;           // clamp to edge 0
            int id = __shfl(my, sel, 64);
            float wgt = (jj < deg) ? 1.f : 0.f;
            v[q] = wgt * bf2f(hb[(size_t)id * 64 + lane]);
        }
        float s0 = (v[0] + v[1]) + (v[2] + v[3]);
        float s1 = (v[4] + v[5]) + (v[6] + v[7]);
        float s2 = (v[8] + v[9]) + (v[10] + v[11]);
        float s3 = (v[12] + v[13]) + (v[14] + v[15]);
        acc += (s0 + s1) + (s2 + s3);
    }
    return acc;
}

// ---- agg1: wave per node, lane = channel (gathers hrelb, 12.8MB ws) --------
__global__ void agg1_kernel(const ushortT* __restrict__ hrelb, const int* __restrict__ eidx,
                            const int* __restrict__ cnt, ushortT* __restrict__ H1b, int N) {
    int node = (int)blockIdx.x * 4 + ((int)threadIdx.x >> 6);
    if (node >= N) return;
    int lane = (int)threadIdx.x & 63;
    int deg = cnt[node];
    int my = (lane < deg) ? eidx[(size_t)node * STRIDE + lane] : 0;
    float acc = bf2f(H1b[(size_t)node * 64 + lane]);
    acc = gather_accum(hrelb, my, deg, lane, acc);
    H1b[(size_t)node * 64 + lane] = f2bf(fmaxf(acc, 0.f));
}

// ---- agg2: aggregate-first layer 2 — gather H1b (6.4MB ws) into S0/S1 ------
__global__ void agg2_kernel(const ushortT* __restrict__ H1b, const int* __restrict__ eidx,
                            const int* __restrict__ cnt, ushortT* __restrict__ Sb, int N) {
    int node = (int)blockIdx.x * 4 + ((int)threadIdx.x >> 6);
    if (node >= N) return;
    int lane = (int)threadIdx.x & 63;
    int deg = cnt[node];
    int my = (lane < deg) ? eidx[(size_t)node * STRIDE + lane] : 0;
    float a0 = 0.f, a1 = 0.f;
    for (int j = 0; j < deg; j += 16) {
        float v[16], w0[16], w1[16];
#pragma unroll
        for (int q = 0; q < 16; ++q) {
            int jj = j + q;
            int sel = (jj < deg) ? jj : 0;
            int id = __shfl(my, sel, 64);       // id = rel*N + src
            int rel = (id >= N) ? 1 : 0;
            int row = id - rel * N;
            float live = (jj < deg) ? 1.f : 0.f;
            w0[q] = rel ? 0.f : live;
            w1[q] = rel ? live : 0.f;
            v[q] = bf2f(H1b[(size_t)row * 64 + lane]);
        }
#pragma unroll
        for (int q = 0; q < 16; ++q) {
            a0 += w0[q] * v[q];
            a1 += w1[q] * v[q];
        }
    }
    Sb[(size_t)node * 64 + lane] = f2bf(a0);               // S0
    Sb[((size_t)N + node) * 64 + lane] = f2bf(a1);         // S1
}

// ---- gemm23: H2 = relu([S0|S1|H1] @ [W2_0;W2_1;loop2] + b2) (MFMA K=192),
//      then layer-3 transform in-register -> hrel3, H3 ----------------------
__global__ __launch_bounds__(256) void gemm23_kernel(
    const ushortT* __restrict__ Sb, const ushortT* __restrict__ H1b,
    const ushortT* __restrict__ BP2, const float* __restrict__ b2,
    const float* __restrict__ W3, const float* __restrict__ loop3,
    const float* __restrict__ b3,
    float* __restrict__ hrel3, float* __restrict__ H3, int N) {
    const int w = (int)threadIdx.x >> 6, lane = (int)threadIdx.x & 63;
    const int rowbase = ((int)blockIdx.x * 4 + w) * 16;
    const int m = lane & 15, quad = lane >> 4;
    const int nclamp = min(rowbase + m, N - 1);

    f32x4 acc[4];
#pragma unroll
    for (int ct = 0; ct < 4; ++ct) acc[ct] = (f32x4){0.f, 0.f, 0.f, 0.f};

#pragma unroll
    for (int ks = 0; ks < 6; ++ks) {
        const ushortT* base =
            (ks < 2) ? (Sb + (size_t)nclamp * 64)
          : (ks < 4) ? (Sb + ((size_t)N + nclamp) * 64)
                     : (H1b + (size_t)nclamp * 64);
        short8 a = *(const short8*)(base + (ks & 1) * 32 + quad * 8);
#pragma unroll
        for (int ct = 0; ct < 4; ++ct) {
            short8 b = *(const short8*)&BP2[((size_t)(ct * 6 + ks) * 64 + lane) * 8];
            acc[ct] = __builtin_amdgcn_mfma_f32_16x16x32_bf16(a, b, acc[ct], 0, 0, 0);
        }
    }

    // bias + relu -> H2 fragment: h2[ct][j] = H2[node=rowbase+quad*4+j][k=ct*16+m]
    float h2[4][4];
#pragma unroll
    for (int ct = 0; ct < 4; ++ct) {
        float bias = b2[ct * 16 + m];
#pragma unroll
        for (int j = 0; j < 4; ++j) h2[ct][j] = fmaxf(acc[ct][j] + bias, 0.f);
    }

    // layer-3 weights for this lane's 4 k-values
    float w3v[4][6];
#pragma unroll
    for (int ct = 0; ct < 4; ++ct) {
        int k = ct * 16 + m;
        w3v[ct][0] = W3[k * 2 + 0];
        w3v[ct][1] = W3[k * 2 + 1];
        w3v[ct][2] = W3[(64 + k) * 2 + 0];
        w3v[ct][3] = W3[(64 + k) * 2 + 1];
        w3v[ct][4] = loop3[k * 2 + 0];
        w3v[ct][5] = loop3[k * 2 + 1];
    }
    float p[4][6];
#pragma unroll
    for (int j = 0; j < 4; ++j)
#pragma unroll
        for (int c = 0; c < 6; ++c) p[j][c] = 0.f;
#pragma unroll
    for (int j = 0; j < 4; ++j)
#pragma unroll
        for (int ct = 0; ct < 4; ++ct)
#pragma unroll
            for (int c = 0; c < 6; ++c) p[j][c] += h2[ct][j] * w3v[ct][c];

    // butterfly over the 16 col-lanes (m bits) within each quad
#pragma unroll
    for (int mask = 1; mask <= 8; mask <<= 1) {
#pragma unroll
        for (int j = 0; j < 4; ++j)
#pragma unroll
            for (int c = 0; c < 6; ++c) p[j][c] += __shfl_xor(p[j][c], mask, 64);
    }

    if (m == 0) {
#pragma unroll
        for (int j = 0; j < 4; ++j) {
            int n = rowbase + quad * 4 + j;
            if (n < N) {
                hrel3[(size_t)n * 2 + 0] = p[j][0];
                hrel3[(size_t)n * 2 + 1] = p[j][1];
                hrel3[((size_t)N + n) * 2 + 0] = p[j][2];
                hrel3[((size_t)N + n) * 2 + 1] = p[j][3];
                H3[(size_t)n * 2 + 0] = p[j][4] + b3[0];
                H3[(size_t)n * 2 + 1] = p[j][5] + b3[1];
            }
        }
    }
}

// ---- K4: layer-3 aggregation + global min (8 predicated outstanding) -------
__global__ void agg3min_kernel(const float* __restrict__ hrel3, const int* __restrict__ eidx,
                               const int* __restrict__ cnt, float* __restrict__ H3,
                               float* __restrict__ minval, int N) {
    int n = (int)blockIdx.x * 256 + (int)threadIdx.x;
    float v = 3.4e38f;
    if (n < N) {
        float a0 = H3[n * 2 + 0], a1 = H3[n * 2 + 1];
        int deg = cnt[n];
        const int* row = &eidx[(size_t)n * STRIDE];
        for (int j = 0; j < deg; j += 8) {
            float2 q[8];
            float wg[8];
#pragma unroll
            for (int qq = 0; qq < 8; ++qq) {
                int jj = j + qq;
                int sel = (jj < deg) ? jj : 0;
                int idx = row[sel];
                wg[qq] = (jj < deg) ? 1.f : 0.f;
                q[qq] = *(const float2*)&hrel3[(size_t)idx * 2];
            }
#pragma unroll
            for (int qq = 0; qq < 8; ++qq) {
                a0 += wg[qq] * q[qq].x;
                a1 += wg[qq] * q[qq].y;
            }
        }
        H3[n * 2 + 0] = a0;
        H3[n * 2 + 1] = a1;
        v = fminf(a0, a1);
    }
#pragma unroll
    for (int mm = 32; mm >= 1; mm >>= 1) v = fminf(v, __shfl_xor(v, mm, 64));
    __shared__ float s[4];
    if ((threadIdx.x & 63) == 0) s[threadIdx.x >> 6] = v;
    __syncthreads();
    if (threadIdx.x == 0)
        atomicMinF(minval, fminf(fminf(s[0], s[1]), fminf(s[2], s[3])));
}

__global__ void mask_kernel(const float* __restrict__ H3, const float* __restrict__ minval,
                            const int* __restrict__ cs, const int* __restrict__ ms,
                            float* __restrict__ out, int N) {
    int n = (int)blockIdx.x * 256 + (int)threadIdx.x;
    if (n >= N) return;
    float m = minval[0] - 1.0f;
    bool up = cs[n] >= ms[n] - 1;
    bool lo = cs[n] == 0;
    out[n * 2 + 0] = up ? m : H3[n * 2 + 0];
    out[n * 2 + 1] = lo ? m : H3[n * 2 + 1];
}

// ---------------------------------------------------------------------------
extern "C" void kernel_launch(void* const* d_in, const int* in_sizes, int n_in,
                              void* d_out, int out_size, void* d_ws, size_t ws_size,
                              hipStream_t stream) {
    const float* x     = (const float*)d_in[0];
    const int* src     = (const int*)d_in[1];
    const int* dst     = (const int*)d_in[2];
    const int* etypes  = (const int*)d_in[3];
    const int* cellsz  = (const int*)d_in[4];
    const int* maxsz   = (const int*)d_in[5];
    const float* W1    = (const float*)d_in[6];
    const float* loop1 = (const float*)d_in[7];
    const float* b1    = (const float*)d_in[8];
    const float* W2    = (const float*)d_in[9];
    const float* loop2 = (const float*)d_in[10];
    const float* b2    = (const float*)d_in[11];
    const float* W3    = (const float*)d_in[12];
    const float* loop3 = (const float*)d_in[13];
    const float* b3    = (const float*)d_in[14];
    float* out = (float*)d_out;

    const int N = in_sizes[0] / 128;  // 50000
    const int E = in_sizes[1];        // 800000

    char* p = (char*)d_ws;
    auto alloc = [&](size_t bytes) -> void* {
        void* r = (void*)p;
        p += ((bytes + 255) / 256) * 256;
        return r;
    };
    ushortT* hrelb  = (ushortT*)alloc((size_t)2 * N * 64 * 2);  // 12.8 MB bf16
    ushortT* H1b    = (ushortT*)alloc((size_t)N * 64 * 2);      //  6.4 MB bf16
    ushortT* Sb     = (ushortT*)alloc((size_t)2 * N * 64 * 2);  // 12.8 MB bf16 (S0,S1)
    float* hrel3    = (float*)alloc((size_t)2 * N * 2 * 4);
    float* H3       = (float*)alloc((size_t)N * 2 * 4);
    int* cnt        = (int*)alloc((size_t)N * 4);
    int* eidx       = (int*)alloc((size_t)N * STRIDE * 4);      // 12.8 MB
    ushortT* BP1    = (ushortT*)alloc((size_t)3072 * 8 * 2);    // 48 KB frag-packed
    ushortT* BP2    = (ushortT*)alloc((size_t)1536 * 8 * 2);    // 24 KB (K=192 x 64)
    float* minval   = (float*)alloc(4);

    const int NBINS = (N + 127) >> 7;                           // 391
    int* bincnt     = (int*)alloc((size_t)NBINS * 4);
    int2* binbuf    = (int2*)alloc((size_t)NBINS * BINCAP * 8); // 8.0 MB
    (void)ws_size; (void)n_in; (void)out_size;

    const int NB_N   = (N + 255) / 256;      // 196
    const int NTILES = (N + 63) / 64;        // 782
    const int NB_W   = (N + 3) / 4;          // 12500
    const int NBA    = (E + 4095) / 4096;    // 196 phase-A blocks

    // K0: weight pack + bincnt/minval init (separate launch: producer ordering)
    pack_init_kernel<<<18, 256, 0, stream>>>(
        W1, loop1, W2, loop2, BP1, BP2, bincnt, minval, NBINS);

    // K1: phase-A binning || layer-1 MFMA GEMM (independent halves)
    k1_kernel<<<NBA + NTILES, 256, 0, stream>>>(
        x, BP1, b1, hrelb, H1b,
        src, dst, etypes, bincnt, binbuf, N, E, NBINS, NBA);

    // K2: phase B — bin-local scatter into eidx buckets + cnt
    phaseB_kernel<<<NBINS, 256, 0, stream>>>(bincnt, binbuf, cnt, eidx, N);

    // layer-1 aggregation: wave per node (gathers hrelb)
    agg1_kernel<<<NB_W, 256, 0, stream>>>(hrelb, eidx, cnt, H1b, N);

    // layer-2 aggregation FIRST: gather H1b (6.4MB ws) into per-rel sums S0/S1
    agg2_kernel<<<NB_W, 256, 0, stream>>>(H1b, eidx, cnt, Sb, N);

    // layer-2 GEMM (K=192 MFMA) + in-register layer-3 transform -> hrel3/H3
    gemm23_kernel<<<NTILES, 256, 0, stream>>>(Sb, H1b, BP2, b2, W3, loop3, b3,
                                              hrel3, H3, N);

    // layer-3 aggregation + global min, then mask
    agg3min_kernel<<<NB_N, 256, 0, stream>>>(hrel3, eidx, cnt, H3, minval, N);
    mask_kernel<<<NB_N, 256, 0, stream>>>(H3, minval, cellsz, maxsz, out, N);
}